// Round 2
// baseline (291.309 us; speedup 1.0000x reference)
//
#include <hip/hip_runtime.h>
#include <cmath>

// K[n,m] = sv^2 * sum_p (x1[n,p]-off)*(x2[m,p]-off) + sb^2,  N=M=8192, P=16.
// Output 256 MiB fp32 -> write-BW-bound (~41 us floor at the fill's 6.5 TB/s).
//
// LDS-free, barrier-free design (rounds 0/1 showed the LDS-pipe + phase
// serialization, not staging VALU or store type, dominated the ~110 us):
//  - Each lane owns 4 output COLUMNS. Its x2 fragment lives in registers:
//    C[c][p] = sv^2*(x2[m][p]-off), 64 VGPR, loaded once per block.
//  - bias[c] = sb^2 - off*sum_p C[c][p]  folds the offset-on-x1 term:
//    out = sum_p x1[n][p]*C[c][p] + bias[c]   (exact algebra, raw x1 reads).
//  - Per row: x1 row = 64 B, wave-uniform address -> scalar/broadcast loads;
//    16 fmac per output; one f32x4 store (wave instr = 1 KiB contiguous).
//  - No LDS, no __syncthreads: pure store stream with ~33% VALU duty,
//    hidden by ~5 resident blocks/CU.
// Block: 256 threads = 4 waves; tile = 32 rows x 1024 cols (128 KiB out).

typedef float f32x4 __attribute__((ext_vector_type(4)));

#define ROWS_PER_BLOCK 32
#define BLOCK_COLS 1024   // 4 waves * 64 lanes * 4 cols

__global__ __launch_bounds__(256, 4) void linear_kernel(
    const float* __restrict__ x1, const float* __restrict__ x2,
    const float* __restrict__ p_lsb, const float* __restrict__ p_lsv,
    const float* __restrict__ p_off, float* __restrict__ out,
    int n, int m)
{
    const int lane = threadIdx.x & 63;
    const int wid  = __builtin_amdgcn_readfirstlane(threadIdx.x >> 6);
    const int c0   = blockIdx.x * BLOCK_COLS + wid * 256 + (lane << 2);
    const int n0   = blockIdx.y * ROWS_PER_BLOCK;

    const float off = p_off[0];
    const float sv  = expf(p_lsv[0]);
    const float sb  = expf(p_lsb[0]);
    const float sv2 = sv * sv;
    const float sb2 = sb * sb;

    // ---- One-time: x2 fragment -> registers (statically indexed, rule #20) ----
    float C[4][16];
    float bias[4];
    #pragma unroll
    for (int c = 0; c < 4; ++c) {
        const f32x4* g = (const f32x4*)(x2 + (size_t)(c0 + c) * 16);
        float s = 0.0f;
        #pragma unroll
        for (int q = 0; q < 4; ++q) {
            f32x4 v = g[q];
            #pragma unroll
            for (int j = 0; j < 4; ++j) {
                const float t = sv2 * (v[j] - off);
                C[c][q * 4 + j] = t;
                s += t;
            }
        }
        bias[c] = sb2 - off * s;
    }

    // ---- Row loop: uniform x1-row load, 64 fmac, one f32x4 store ----
    float* orow = out + (size_t)n0 * m + c0;
    const f32x4* arow = (const f32x4*)(x1 + (size_t)n0 * 16);
    #pragma unroll 2
    for (int r = 0; r < ROWS_PER_BLOCK; ++r) {
        const f32x4 a0 = arow[0];
        const f32x4 a1 = arow[1];
        const f32x4 a2 = arow[2];
        const f32x4 a3 = arow[3];
        float a[16];
        #pragma unroll
        for (int j = 0; j < 4; ++j) {
            a[j]      = a0[j];
            a[4 + j]  = a1[j];
            a[8 + j]  = a2[j];
            a[12 + j] = a3[j];
        }
        f32x4 acc;
        acc[0] = bias[0]; acc[1] = bias[1]; acc[2] = bias[2]; acc[3] = bias[3];
        #pragma unroll
        for (int p = 0; p < 16; ++p) {
            acc[0] = fmaf(a[p], C[0][p], acc[0]);
            acc[1] = fmaf(a[p], C[1][p], acc[1]);
            acc[2] = fmaf(a[p], C[2][p], acc[2]);
            acc[3] = fmaf(a[p], C[3][p], acc[3]);
        }
        *(f32x4*)orow = acc;
        orow += m;
        arow += 4;
    }
}

extern "C" void kernel_launch(void* const* d_in, const int* in_sizes, int n_in,
                              void* d_out, int out_size, void* d_ws, size_t ws_size,
                              hipStream_t stream) {
    const float* x1  = (const float*)d_in[0];
    const float* x2  = (const float*)d_in[1];
    const float* lsb = (const float*)d_in[2];
    const float* lsv = (const float*)d_in[3];
    const float* off = (const float*)d_in[4];
    float* out = (float*)d_out;

    const int n = in_sizes[0] / 16;   // 8192
    const int m = in_sizes[1] / 16;   // 8192

    dim3 grid(m / BLOCK_COLS, n / ROWS_PER_BLOCK);   // 8 x 256 = 2048 blocks
    linear_kernel<<<grid, 256, 0, stream>>>(x1, x2, lsb, lsv, off, out, n, m);
}